// Round 11
// baseline (1115.576 us; speedup 1.0000x reference)
//
#include <hip/hip_runtime.h>

typedef unsigned short u16;
typedef unsigned int   u32;

#define B_   128
#define S_   48
#define H_   100
#define G_   400
#define PXP  1120   // px/hx row pitch (1116 used, padded)

__device__ __forceinline__ float b2f(u16 u) {
    union { u32 i; float f; } v; v.i = ((u32)u) << 16; return v.f;
}
__device__ __forceinline__ u16 f2b(float f) {
    union { float f; u32 i; } v; v.f = f;
    u32 r = v.i + 0x7FFF + ((v.i >> 16) & 1);
    return (u16)(r >> 16);
}
__device__ __forceinline__ float sigf(float x) { return 1.f / (1.f + expf(-x)); }

// fast, overflow-safe activation forms (v_exp based; err ~1e-6 vs libm)
__device__ __forceinline__ float fsig(float x) { return 1.f / (1.f + __expf(-x)); }
__device__ __forceinline__ float ftanh(float x) {
    const float t = __expf(-2.f * fabsf(x));   // t in (0,1], no overflow
    const float r = (1.f - t) / (1.f + t);
    return copysignf(r, x);
}

// wave-uniform broadcast of h[u] held across two per-lane registers
__device__ __forceinline__ float rl(float v0, float v1, int u) {
    return __int_as_float(
        u < 64 ? __builtin_amdgcn_readlane(__float_as_int(v0), u)
               : __builtin_amdgcn_readlane(__float_as_int(v1), u - 64));
}

// dtype-flexible weight load: bf==1 -> bf16 storage, bf==0 -> fp32 storage
__device__ __forceinline__ float ldw(const void* p, long i, int bf) {
    return bf ? b2f(((const u16*)p)[i]) : ((const float*)p)[i];
}

// ---------------------------------------------------------------------------
// Dtype probe (proven in the passing runs).
// ---------------------------------------------------------------------------
__global__ __launch_bounds__(256) void detect_kernel(const void* wemb, int* flag)
{
    const int t = threadIdx.x;
    __shared__ int s;
    if (t == 0) s = 0;
    __syncthreads();
    int bad = 0;
    const u16* p = (const u16*)wemb;
    for (int i = t; i < 4096; i += 256) {
        float v = b2f(p[i]);
        if (!(fabsf(v) < 1e4f)) bad = 1;
    }
    if (bad) atomicOr(&s, 1);
    __syncthreads();
    if (t == 0) *flag = s ? 0 : 1;
}

// ---------------------------------------------------------------------------
// Embedding: word gather + char conv/maxpool.  grid (B, S, 2), block 64.
// ---------------------------------------------------------------------------
__global__ __launch_bounds__(64) void embed_kernel(
    const int* __restrict__ qw, const int* __restrict__ qc,
    const int* __restrict__ sw, const int* __restrict__ sc,
    const void* __restrict__ wemb, const void* __restrict__ cemb,
    const void* __restrict__ cw, const void* __restrict__ cb,
    float* __restrict__ px, float* __restrict__ hx, const int* __restrict__ flagp)
{
    const int bf = *flagp;
    const int b = blockIdx.x, s = blockIdx.y, seq = blockIdx.z;
    const int* words = seq ? sw : qw;
    const int* chars = seq ? sc : qc;
    float* dst = seq ? hx : px;
    const int t = threadIdx.x;

    float* row = dst + (long)(s * B_ + b) * PXP;
    const int w = words[b * S_ + s];
    for (int d = t; d < 300; d += 64) row[d] = ldw(wemb, (long)w * 300 + d, bf);

    __shared__ float ce[256];
    const int* ch = chars + (b * S_ + s) * 16;
    for (int j = t; j < 256; j += 64) {
        int ci = ch[j >> 4];
        ce[j] = ldw(cemb, ci * 16 + (j & 15), bf);
    }
    __syncthreads();

    float cwr[3][16], cbr[16];
#pragma unroll
    for (int oc = 0; oc < 16; ++oc) {
        cbr[oc] = ldw(cb, oc, bf);
#pragma unroll
        for (int kk = 0; kk < 3; ++kk) cwr[kk][oc] = ldw(cw, oc * 3 + kk, bf);
    }

    float vmax[16];
#pragma unroll
    for (int oc = 0; oc < 16; ++oc) vmax[oc] = -1e30f;

    for (int p = t; p < 254; p += 64) {
        float c0 = ce[p], c1 = ce[p + 1], c2 = ce[p + 2];
#pragma unroll
        for (int oc = 0; oc < 16; ++oc) {
            float v = fmaf(c0, cwr[0][oc], fmaf(c1, cwr[1][oc], fmaf(c2, cwr[2][oc], cbr[oc])));
            vmax[oc] = fmaxf(vmax[oc], v);
        }
    }
#pragma unroll
    for (int m = 32; m; m >>= 1) {
#pragma unroll
        for (int oc = 0; oc < 16; ++oc)
            vmax[oc] = fmaxf(vmax[oc], __shfl_xor(vmax[oc], m));
    }
    if (t == 0) {
#pragma unroll
        for (int oc = 0; oc < 16; ++oc) {
            float v = vmax[oc];
            if (b != 0) v = fmaxf(v, 0.f);   // ref quirk: batch row 0 skips relu
            row[300 + oc] = v;
        }
    }
}

// ---------------------------------------------------------------------------
// Xg = X @ wih^T + (bih + bhh).  grid (96, 7, 2), block 256.
// gfx950: bf16 MFMA 64x64 tile (BK=64).  Other archs: proven vector path.
// ---------------------------------------------------------------------------
#if defined(__gfx950__)

typedef __attribute__((ext_vector_type(4))) float f32x4;
typedef __attribute__((ext_vector_type(8))) __bf16 bf16x8;
#define LDP 72   // u16 pitch; 144 B = 9x16B rows, all b128 reads 16B-aligned

__global__ __launch_bounds__(256) void gemm_wih(
    const float* __restrict__ px, const float* __restrict__ hx,
    float* __restrict__ Xg_p, float* __restrict__ Xg_h,
    const void* __restrict__ wih, const void* __restrict__ bih,
    const void* __restrict__ bhh, int K, const int* __restrict__ flagp)
{
    const int bf = *flagp;
    const float* A = blockIdx.z ? hx : px;
    float* C = blockIdx.z ? Xg_h : Xg_p;
    const int m0 = blockIdx.x * 64, n0 = blockIdx.y * 64;

    __shared__ __align__(16) u16 As[64 * LDP];
    __shared__ __align__(16) u16 Bs[64 * LDP];

    const int tid = threadIdx.x;
    const int r  = tid >> 2;          // staging row 0..63
    const int kc = (tid & 3) * 16;    // k-chunk within row

    const int lane = tid & 63;
    const int w    = tid >> 6;        // wave 0..3
    const int fr   = lane & 15;
    const int fq   = lane >> 4;

    const u16* wp = (const u16*)wih;

    f32x4 acc[4] = {};

    for (int k0 = 0; k0 < K; k0 += 64) {
        u16* as = &As[r * LDP + kc];
        u16* bs = &Bs[r * LDP + kc];
        const int n = n0 + r;
        const float* ap = A + (long)(m0 + r) * PXP + k0 + kc;
        if (k0 + 64 <= K) {
            // fast path: full tile in-bounds
#pragma unroll
            for (int c = 0; c < 4; ++c) {
                float4 v = *(const float4*)(ap + c * 4);
                as[c * 4 + 0] = f2b(v.x); as[c * 4 + 1] = f2b(v.y);
                as[c * 4 + 2] = f2b(v.z); as[c * 4 + 3] = f2b(v.w);
            }
            if (n < G_) {
                const u16* bp = wp + (long)n * K + k0 + kc;
#pragma unroll
                for (int i = 0; i < 16; ++i) bs[i] = bp[i];
            } else {
#pragma unroll
                for (int i = 0; i < 16; ++i) bs[i] = 0;
            }
        } else {
            // K-tail: scalar masked
            const float* ar = A + (long)(m0 + r) * PXP;
            const u16*   br = wp + (long)n * K;
            const int nok = n < G_;
#pragma unroll
            for (int i = 0; i < 16; ++i) {
                const int k = k0 + kc + i;
                as[i] = (k < K) ? f2b(ar[k]) : (u16)0;
                bs[i] = (nok && k < K) ? br[k] : (u16)0;
            }
        }
        __syncthreads();

#pragma unroll
        for (int ks = 0; ks < 64; ks += 32) {
            bf16x8 af = *(const bf16x8*)&As[(w * 16 + fr) * LDP + ks + fq * 8];
#pragma unroll
            for (int j = 0; j < 4; ++j) {
                bf16x8 bj = *(const bf16x8*)&Bs[(j * 16 + fr) * LDP + ks + fq * 8];
                acc[j] = __builtin_amdgcn_mfma_f32_16x16x32_bf16(af, bj, acc[j], 0, 0, 0);
            }
        }
        __syncthreads();
    }

    // D layout (m89-verified): lane holds D[row=fq*4+i][col=fr] per 16x16 tile
#pragma unroll
    for (int j = 0; j < 4; ++j) {
        const int col = n0 + j * 16 + fr;
        if (col < G_) {
            const float bias = ldw(bih, col, bf) + ldw(bhh, col, bf);
#pragma unroll
            for (int i = 0; i < 4; ++i) {
                const int row = m0 + w * 16 + fq * 4 + i;
                C[(long)row * G_ + col] = acc[j][i] + bias;
            }
        }
    }
}
#undef LDP

#else  // !__gfx950__ — proven vector fallback (never runs on gfx950)

__global__ __launch_bounds__(256) void gemm_wih(
    const float* __restrict__ px, const float* __restrict__ hx,
    float* __restrict__ Xg_p, float* __restrict__ Xg_h,
    const void* __restrict__ wih, const void* __restrict__ bih,
    const void* __restrict__ bhh, int K, const int* __restrict__ flagp)
{
    const int bf = *flagp;
    const float* A = blockIdx.z ? hx : px;
    float* C = blockIdx.z ? Xg_h : Xg_p;

    __shared__ float As[16][64];
    __shared__ float Bs[16][64];

    const int tid = threadIdx.x;
    const int tx = tid & 15, ty = tid >> 4;
    const int m0 = blockIdx.x * 64, n0 = blockIdx.y * 64;
    const int lr = tid >> 2, lk = (tid & 3) * 4;

    float acc[4][4] = {};

    for (int k0 = 0; k0 < K; k0 += 16) {
        const float* Ap = A + (long)(m0 + lr) * PXP + k0 + lk;
#pragma unroll
        for (int u = 0; u < 4; ++u)
            As[lk + u][lr] = (k0 + lk + u < K) ? Ap[u] : 0.f;
        {
            const int n = n0 + lr;
#pragma unroll
            for (int u = 0; u < 4; ++u) {
                const int kk = k0 + lk + u;
                Bs[lk + u][lr] = (n < G_ && kk < K) ? ldw(wih, (long)n * K + kk, bf) : 0.f;
            }
        }
        __syncthreads();
#pragma unroll
        for (int k = 0; k < 16; ++k) {
            float a[4], bq[4];
#pragma unroll
            for (int i = 0; i < 4; ++i) a[i] = As[k][ty * 4 + i];
#pragma unroll
            for (int j = 0; j < 4; ++j) bq[j] = Bs[k][tx * 4 + j];
#pragma unroll
            for (int i = 0; i < 4; ++i)
#pragma unroll
                for (int j = 0; j < 4; ++j)
                    acc[i][j] = fmaf(a[i], bq[j], acc[i][j]);
        }
        __syncthreads();
    }

#pragma unroll
    for (int j = 0; j < 4; ++j) {
        const int col = n0 + tx * 4 + j;
        if (col < G_) {
            const float bias = ldw(bih, col, bf) + ldw(bhh, col, bf);
#pragma unroll
            for (int i = 0; i < 4; ++i)
                C[(long)(m0 + ty * 4 + i) * G_ + col] = acc[i][j] + bias;
        }
    }
}

#endif

// ---------------------------------------------------------------------------
// LSTM scan: one WG per (sample, sequence).  grid (128, 2), block 448.
// wrow[100] is PINNED into VGPRs via empty inline-asm ("+v"): rounds 7-10
// showed the register allocator rematerializes invariant loads every step
// (1 GB/dispatch of uncoalesced L2 re-reads, 75 us) no matter what budget
// hints we give.  The asm makes each weight the output of an opaque op the
// RA cannot rematerialize.  __launch_bounds__(448,2) permits up to 256 VGPR
// (we run 1 block/CU = max 2 waves/SIMD, so nothing to lose).
// ---------------------------------------------------------------------------
__global__ __launch_bounds__(448, 2)
void lstm_scan(
    const float* __restrict__ Xg_p, const float* __restrict__ Xg_h,
    const void* __restrict__ whh,
    float* __restrict__ p_h, float* __restrict__ h_h,
    float* __restrict__ px, float* __restrict__ hx, int cat_off,
    const int* __restrict__ flagp)
{
    const int bf = *flagp;
    const int b = blockIdx.x, seq = blockIdx.y;
    const float* Xg = seq ? Xg_h : Xg_p;
    float* hout = seq ? h_h : p_h;
    float* xcat = seq ? hx : px;
    const int g = threadIdx.x;
    const int l = g & 63;

    __shared__ float h_lds[128];             // h (100 used, padded)
    __shared__ float g_lds[400];             // gate pre-activations
    __shared__ float h_hist[S_ * 104];       // h history, flushed at end

    float wrow[100];
    float xg = 0.f;
    if (g < G_) {
#pragma unroll
        for (int j = 0; j < 100; ++j) wrow[j] = ldw(whh, (long)g * 100 + j, bf);
#pragma unroll
        for (int j = 0; j < 100; ++j) asm volatile("" : "+v"(wrow[j]));  // pin
        xg = Xg[(long)b * G_ + g];
    }
    if (g < 128) h_lds[g] = 0.f;
    float c_reg = 0.f;
    __syncthreads();

    for (int s = 0; s < S_; ++s) {
        // per-wave copy of h (2 LDS reads), broadcast via readlane below
        const float hv0 = h_lds[l];
        const float hv1 = h_lds[l + 64];
        if (g < G_) {
            float a0 = xg, a1 = 0.f, a2 = 0.f, a3 = 0.f;
#pragma unroll
            for (int u = 0; u < 100; u += 4) {
                a0 = fmaf(rl(hv0, hv1, u),     wrow[u],     a0);
                a1 = fmaf(rl(hv0, hv1, u + 1), wrow[u + 1], a1);
                a2 = fmaf(rl(hv0, hv1, u + 2), wrow[u + 2], a2);
                a3 = fmaf(rl(hv0, hv1, u + 3), wrow[u + 3], a3);
            }
            g_lds[g] = (a0 + a1) + (a2 + a3);
            if (s + 1 < S_) xg = Xg[(long)((s + 1) * B_ + b) * G_ + g];  // prefetch
        }
        __syncthreads();
        if (g < H_) {
            const float iv = fsig(g_lds[g]);
            const float fv = fsig(g_lds[100 + g]);
            const float gv = ftanh(g_lds[200 + g]);
            const float ov = fsig(g_lds[300 + g]);
            c_reg = fv * c_reg + iv * gv;
            const float hv = ov * ftanh(c_reg);
            h_lds[g] = hv;
            h_hist[s * 104 + g] = hv;
        }
        __syncthreads();
    }

    // coalesced flush of the whole h history
    for (int i = g; i < S_ * H_; i += 448) {
        const int s = i / H_, d = i - s * H_;
        const float hv = h_hist[s * 104 + d];
        hout[(long)(s * B_ + b) * H_ + d] = hv;
        if (cat_off >= 0) xcat[(long)(s * B_ + b) * PXP + cat_off + d] = hv;
    }
}

// ---------------------------------------------------------------------------
// Cross attention for one batch sample.  grid (128), block 256.
// ---------------------------------------------------------------------------
__global__ __launch_bounds__(256) void attn_kernel(
    const float* __restrict__ p_h, const float* __restrict__ h_h,
    float* __restrict__ px, float* __restrict__ hx, int off)
{
    const int b = blockIdx.x, t = threadIdx.x;
    __shared__ float P[4800], Q[4800], A[2304], Sx[2304];

    for (int i = t; i < 4800; i += 256) {
        const int s = i / 100, d = i % 100;
        P[i] = p_h[(long)(s * B_ + b) * H_ + d];
        Q[i] = h_h[(long)(s * B_ + b) * H_ + d];
    }
    __syncthreads();

    for (int e = t; e < 2304; e += 256) {
        const int p = e / 48, q = e % 48;
        float acc = 0.f;
        for (int j = 0; j < 100; ++j) acc = fmaf(P[p * 100 + j], Q[q * 100 + j], acc);
        A[e] = acc;
    }
    __syncthreads();

    if (t < 48) {  // row softmax
        float m = -1e30f;
        for (int q = 0; q < 48; ++q) m = fmaxf(m, A[t * 48 + q]);
        float sum = 0.f;
        for (int q = 0; q < 48; ++q) sum += expf(A[t * 48 + q] - m);
        const float inv = 1.f / sum;
        for (int q = 0; q < 48; ++q) Sx[t * 48 + q] = expf(A[t * 48 + q] - m) * inv;
    }
    __syncthreads();

    for (int e = t; e < 4800; e += 256) {  // a_p = S @ Q
        const int p = e / 100, d = e % 100;
        float acc = 0.f;
        for (int q = 0; q < 48; ++q) acc = fmaf(Sx[p * 48 + q], Q[q * 100 + d], acc);
        px[(long)(p * B_ + b) * PXP + off + d] = acc;
    }
    __syncthreads();

    if (t < 48) {  // col softmax
        float m = -1e30f;
        for (int p = 0; p < 48; ++p) m = fmaxf(m, A[p * 48 + t]);
        float sum = 0.f;
        for (int p = 0; p < 48; ++p) sum += expf(A[p * 48 + t] - m);
        const float inv = 1.f / sum;
        for (int p = 0; p < 48; ++p) Sx[p * 48 + t] = expf(A[p * 48 + t] - m) * inv;
    }
    __syncthreads();

    for (int e = t; e < 4800; e += 256) {  // a_h[q] = sum_p S2[p][q] * P[p]
        const int q = e / 100, d = e % 100;
        float acc = 0.f;
        for (int p = 0; p < 48; ++p) acc = fmaf(Sx[p * 48 + q], P[p * 100 + d], acc);
        hx[(long)(q * B_ + b) * PXP + off + d] = acc;
    }
}

// ---------------------------------------------------------------------------
// Pool + feature build.
// ---------------------------------------------------------------------------
__global__ __launch_bounds__(256) void pool_feats(
    const float* __restrict__ p_h, const float* __restrict__ h_h,
    float* __restrict__ feats)
{
    const int t = blockIdx.x * 256 + threadIdx.x;
    if (t >= B_ * H_) return;
    const int b = t / H_, u = t % H_;
    float hq = -1e30f, hs = -1e30f;
    for (int s = 0; s < S_; ++s) {
        hq = fmaxf(hq, p_h[(long)(s * B_ + b) * H_ + u]);
        hs = fmaxf(hs, h_h[(long)(s * B_ + b) * H_ + u]);
    }
    float* f = feats + b * 500;
    f[u]       = hq;
    f[100 + u] = hs;
    f[200 + u] = hs - hq;
    f[300 + u] = hq * hs;
    f[400 + u] = fabsf(hq - hs);
}

// ---------------------------------------------------------------------------
// z = relu(feats @ fcl_w^T + fcl_b).
// ---------------------------------------------------------------------------
__global__ __launch_bounds__(256) void fcl_kernel(
    const float* __restrict__ feats, const void* __restrict__ fw,
    const void* __restrict__ fb, float* __restrict__ z, const int* __restrict__ flagp)
{
    const int bf = *flagp;
    const int t = blockIdx.x * 256 + threadIdx.x;
    const int o = t >> 7, b = t & 127;
    float acc = ldw(fb, o, bf);
    const float* f = feats + b * 500;
    for (int d = 0; d < 500; ++d) acc = fmaf(f[d], ldw(fw, (long)o * 500 + d, bf), acc);
    z[b * 800 + o] = fmaxf(acc, 0.f);
}

// ---------------------------------------------------------------------------
// out = sigmoid(z @ last_w^T + last_b).  Output dtype follows flag.
// ---------------------------------------------------------------------------
__global__ __launch_bounds__(256) void last_kernel(
    const float* __restrict__ z, const void* __restrict__ lw,
    const void* __restrict__ lb, void* __restrict__ out, const int* __restrict__ flagp)
{
    const int bf = *flagp;
    const int t = threadIdx.x;
    const int b = t >> 1, c = t & 1;
    float acc = ldw(lb, c, bf);
    const float* zr = z + b * 800;
    for (int o = 0; o < 800; ++o) acc = fmaf(zr[o], ldw(lw, (long)c * 800 + o, bf), acc);
    const float v = 1.f / (1.f + expf(-acc));
    if (bf) ((u16*)out)[t] = f2b(v);
    else    ((float*)out)[t] = v;
}

// ---------------------------------------------------------------------------
extern "C" void kernel_launch(void* const* d_in, const int* in_sizes, int n_in,
                              void* d_out, int out_size, void* d_ws, size_t ws_size,
                              hipStream_t stream)
{
    (void)in_sizes; (void)n_in; (void)out_size; (void)ws_size;

    const int* qw = (const int*)d_in[0];
    const int* qc = (const int*)d_in[1];
    const int* sw = (const int*)d_in[2];
    const int* sc = (const int*)d_in[3];
    const void* wemb = d_in[4];
    const void* cemb = d_in[5];
    const void* cw   = d_in[6];
    const void* cb   = d_in[7];
    const void* fclw = d_in[28];
    const void* fclb = d_in[29];
    const void* lw   = d_in[30];
    const void* lb   = d_in[31];

    float* ws = (float*)d_ws;
    int*  flag = (int*)ws;                               // [16] floats reserved
    float* px   = ws + 16;
    float* hx   = px + (long)S_ * B_ * PXP;
    float* Xg_p = hx + (long)S_ * B_ * PXP;
    float* Xg_h = Xg_p + (long)S_ * B_ * G_;
    float* p_h  = Xg_h + (long)S_ * B_ * G_;
    float* h_h  = p_h + (long)S_ * B_ * H_;
    float* feats = h_h + (long)S_ * B_ * H_;
    float* z    = feats + B_ * 500;

    detect_kernel<<<dim3(1), 256, 0, stream>>>(wemb, flag);

    embed_kernel<<<dim3(B_, S_, 2), 64, 0, stream>>>(qw, qc, sw, sc, wemb, cemb, cw, cb, px, hx, flag);

    for (int k = 0; k < 5; ++k) {
        const void* wih = d_in[8 + 4 * k];
        const void* whh = d_in[9 + 4 * k];
        const void* bih = d_in[10 + 4 * k];
        const void* bhh = d_in[11 + 4 * k];
        const int K = 316 + 200 * k;

        gemm_wih<<<dim3(96, 7, 2), 256, 0, stream>>>(px, hx, Xg_p, Xg_h, wih, bih, bhh, K, flag);

        const int cat = (k < 4) ? (K + 100) : -1;
        lstm_scan<<<dim3(B_, 2), 448, 0, stream>>>(Xg_p, Xg_h, whh, p_h, h_h, px, hx, cat, flag);

        if (k < 4)
            attn_kernel<<<dim3(B_), 256, 0, stream>>>(p_h, h_h, px, hx, K);
    }

    pool_feats<<<dim3(50), 256, 0, stream>>>(p_h, h_h, feats);
    fcl_kernel<<<dim3(400), 256, 0, stream>>>(feats, fclw, fclb, z, flag);
    last_kernel<<<dim3(1), 256, 0, stream>>>(z, lw, lb, d_out, flag);
}

// Round 12
// 1020.961 us; speedup vs baseline: 1.0927x; 1.0927x over previous
//
#include <hip/hip_runtime.h>

typedef unsigned short u16;
typedef unsigned int   u32;

#define B_   128
#define S_   48
#define H_   100
#define G_   400
#define PXP  1120   // px/hx row pitch (1116 used, padded)

__device__ __forceinline__ float b2f(u16 u) {
    union { u32 i; float f; } v; v.i = ((u32)u) << 16; return v.f;
}
__device__ __forceinline__ u16 f2b(float f) {
    union { float f; u32 i; } v; v.f = f;
    u32 r = v.i + 0x7FFF + ((v.i >> 16) & 1);
    return (u16)(r >> 16);
}
__device__ __forceinline__ float sigf(float x) { return 1.f / (1.f + expf(-x)); }

// fast, overflow-safe activation forms (v_exp based; err ~1e-6 vs libm)
__device__ __forceinline__ float fsig(float x) { return 1.f / (1.f + __expf(-x)); }
__device__ __forceinline__ float ftanh(float x) {
    const float t = __expf(-2.f * fabsf(x));   // t in (0,1], no overflow
    const float r = (1.f - t) / (1.f + t);
    return copysignf(r, x);
}

// wave-uniform broadcast of h[u] held across two per-lane registers
__device__ __forceinline__ float rl(float v0, float v1, int u) {
    return __int_as_float(
        u < 64 ? __builtin_amdgcn_readlane(__float_as_int(v0), u)
               : __builtin_amdgcn_readlane(__float_as_int(v1), u - 64));
}

// dtype-flexible weight load: bf==1 -> bf16 storage, bf==0 -> fp32 storage
__device__ __forceinline__ float ldw(const void* p, long i, int bf) {
    return bf ? b2f(((const u16*)p)[i]) : ((const float*)p)[i];
}

// ---------------------------------------------------------------------------
// Dtype probe (proven in the passing runs).
// ---------------------------------------------------------------------------
__global__ __launch_bounds__(256) void detect_kernel(const void* wemb, int* flag)
{
    const int t = threadIdx.x;
    __shared__ int s;
    if (t == 0) s = 0;
    __syncthreads();
    int bad = 0;
    const u16* p = (const u16*)wemb;
    for (int i = t; i < 4096; i += 256) {
        float v = b2f(p[i]);
        if (!(fabsf(v) < 1e4f)) bad = 1;
    }
    if (bad) atomicOr(&s, 1);
    __syncthreads();
    if (t == 0) *flag = s ? 0 : 1;
}

// ---------------------------------------------------------------------------
// Embedding: word gather + char conv/maxpool.  grid (B, S, 2), block 64.
// ---------------------------------------------------------------------------
__global__ __launch_bounds__(64) void embed_kernel(
    const int* __restrict__ qw, const int* __restrict__ qc,
    const int* __restrict__ sw, const int* __restrict__ sc,
    const void* __restrict__ wemb, const void* __restrict__ cemb,
    const void* __restrict__ cw, const void* __restrict__ cb,
    float* __restrict__ px, float* __restrict__ hx, const int* __restrict__ flagp)
{
    const int bf = *flagp;
    const int b = blockIdx.x, s = blockIdx.y, seq = blockIdx.z;
    const int* words = seq ? sw : qw;
    const int* chars = seq ? sc : qc;
    float* dst = seq ? hx : px;
    const int t = threadIdx.x;

    float* row = dst + (long)(s * B_ + b) * PXP;
    const int w = words[b * S_ + s];
    for (int d = t; d < 300; d += 64) row[d] = ldw(wemb, (long)w * 300 + d, bf);

    __shared__ float ce[256];
    const int* ch = chars + (b * S_ + s) * 16;
    for (int j = t; j < 256; j += 64) {
        int ci = ch[j >> 4];
        ce[j] = ldw(cemb, ci * 16 + (j & 15), bf);
    }
    __syncthreads();

    float cwr[3][16], cbr[16];
#pragma unroll
    for (int oc = 0; oc < 16; ++oc) {
        cbr[oc] = ldw(cb, oc, bf);
#pragma unroll
        for (int kk = 0; kk < 3; ++kk) cwr[kk][oc] = ldw(cw, oc * 3 + kk, bf);
    }

    float vmax[16];
#pragma unroll
    for (int oc = 0; oc < 16; ++oc) vmax[oc] = -1e30f;

    for (int p = t; p < 254; p += 64) {
        float c0 = ce[p], c1 = ce[p + 1], c2 = ce[p + 2];
#pragma unroll
        for (int oc = 0; oc < 16; ++oc) {
            float v = fmaf(c0, cwr[0][oc], fmaf(c1, cwr[1][oc], fmaf(c2, cwr[2][oc], cbr[oc])));
            vmax[oc] = fmaxf(vmax[oc], v);
        }
    }
#pragma unroll
    for (int m = 32; m; m >>= 1) {
#pragma unroll
        for (int oc = 0; oc < 16; ++oc)
            vmax[oc] = fmaxf(vmax[oc], __shfl_xor(vmax[oc], m));
    }
    if (t == 0) {
#pragma unroll
        for (int oc = 0; oc < 16; ++oc) {
            float v = vmax[oc];
            if (b != 0) v = fmaxf(v, 0.f);   // ref quirk: batch row 0 skips relu
            row[300 + oc] = v;
        }
    }
}

// ---------------------------------------------------------------------------
// Xg = X @ wih^T + (bih + bhh).  grid (96, 7, 2), block 256.
// gfx950: bf16 MFMA 64x64 tile (BK=64).  Other archs: proven vector path.
// ---------------------------------------------------------------------------
#if defined(__gfx950__)

typedef __attribute__((ext_vector_type(4))) float f32x4;
typedef __attribute__((ext_vector_type(8))) __bf16 bf16x8;
#define LDP 72   // u16 pitch; 144 B = 9x16B rows, all b128 reads 16B-aligned

__global__ __launch_bounds__(256) void gemm_wih(
    const float* __restrict__ px, const float* __restrict__ hx,
    float* __restrict__ Xg_p, float* __restrict__ Xg_h,
    const void* __restrict__ wih, const void* __restrict__ bih,
    const void* __restrict__ bhh, int K, const int* __restrict__ flagp)
{
    const int bf = *flagp;
    const float* A = blockIdx.z ? hx : px;
    float* C = blockIdx.z ? Xg_h : Xg_p;
    const int m0 = blockIdx.x * 64, n0 = blockIdx.y * 64;

    __shared__ __align__(16) u16 As[64 * LDP];
    __shared__ __align__(16) u16 Bs[64 * LDP];

    const int tid = threadIdx.x;
    const int r  = tid >> 2;          // staging row 0..63
    const int kc = (tid & 3) * 16;    // k-chunk within row

    const int lane = tid & 63;
    const int w    = tid >> 6;        // wave 0..3
    const int fr   = lane & 15;
    const int fq   = lane >> 4;

    const u16* wp = (const u16*)wih;

    f32x4 acc[4] = {};

    for (int k0 = 0; k0 < K; k0 += 64) {
        u16* as = &As[r * LDP + kc];
        u16* bs = &Bs[r * LDP + kc];
        const int n = n0 + r;
        const float* ap = A + (long)(m0 + r) * PXP + k0 + kc;
        if (k0 + 64 <= K) {
            // fast path: full tile in-bounds
#pragma unroll
            for (int c = 0; c < 4; ++c) {
                float4 v = *(const float4*)(ap + c * 4);
                as[c * 4 + 0] = f2b(v.x); as[c * 4 + 1] = f2b(v.y);
                as[c * 4 + 2] = f2b(v.z); as[c * 4 + 3] = f2b(v.w);
            }
            if (n < G_) {
                const u16* bp = wp + (long)n * K + k0 + kc;
#pragma unroll
                for (int i = 0; i < 16; ++i) bs[i] = bp[i];
            } else {
#pragma unroll
                for (int i = 0; i < 16; ++i) bs[i] = 0;
            }
        } else {
            // K-tail: scalar masked
            const float* ar = A + (long)(m0 + r) * PXP;
            const u16*   br = wp + (long)n * K;
            const int nok = n < G_;
#pragma unroll
            for (int i = 0; i < 16; ++i) {
                const int k = k0 + kc + i;
                as[i] = (k < K) ? f2b(ar[k]) : (u16)0;
                bs[i] = (nok && k < K) ? br[k] : (u16)0;
            }
        }
        __syncthreads();

#pragma unroll
        for (int ks = 0; ks < 64; ks += 32) {
            bf16x8 af = *(const bf16x8*)&As[(w * 16 + fr) * LDP + ks + fq * 8];
#pragma unroll
            for (int j = 0; j < 4; ++j) {
                bf16x8 bj = *(const bf16x8*)&Bs[(j * 16 + fr) * LDP + ks + fq * 8];
                acc[j] = __builtin_amdgcn_mfma_f32_16x16x32_bf16(af, bj, acc[j], 0, 0, 0);
            }
        }
        __syncthreads();
    }

    // D layout (m89-verified): lane holds D[row=fq*4+i][col=fr] per 16x16 tile
#pragma unroll
    for (int j = 0; j < 4; ++j) {
        const int col = n0 + j * 16 + fr;
        if (col < G_) {
            const float bias = ldw(bih, col, bf) + ldw(bhh, col, bf);
#pragma unroll
            for (int i = 0; i < 4; ++i) {
                const int row = m0 + w * 16 + fq * 4 + i;
                C[(long)row * G_ + col] = acc[j][i] + bias;
            }
        }
    }
}
#undef LDP

#else  // !__gfx950__ — proven vector fallback (never runs on gfx950)

__global__ __launch_bounds__(256) void gemm_wih(
    const float* __restrict__ px, const float* __restrict__ hx,
    float* __restrict__ Xg_p, float* __restrict__ Xg_h,
    const void* __restrict__ wih, const void* __restrict__ bih,
    const void* __restrict__ bhh, int K, const int* __restrict__ flagp)
{
    const int bf = *flagp;
    const float* A = blockIdx.z ? hx : px;
    float* C = blockIdx.z ? Xg_h : Xg_p;

    __shared__ float As[16][64];
    __shared__ float Bs[16][64];

    const int tid = threadIdx.x;
    const int tx = tid & 15, ty = tid >> 4;
    const int m0 = blockIdx.x * 64, n0 = blockIdx.y * 64;
    const int lr = tid >> 2, lk = (tid & 3) * 4;

    float acc[4][4] = {};

    for (int k0 = 0; k0 < K; k0 += 16) {
        const float* Ap = A + (long)(m0 + lr) * PXP + k0 + lk;
#pragma unroll
        for (int u = 0; u < 4; ++u)
            As[lk + u][lr] = (k0 + lk + u < K) ? Ap[u] : 0.f;
        {
            const int n = n0 + lr;
#pragma unroll
            for (int u = 0; u < 4; ++u) {
                const int kk = k0 + lk + u;
                Bs[lk + u][lr] = (n < G_ && kk < K) ? ldw(wih, (long)n * K + kk, bf) : 0.f;
            }
        }
        __syncthreads();
#pragma unroll
        for (int k = 0; k < 16; ++k) {
            float a[4], bq[4];
#pragma unroll
            for (int i = 0; i < 4; ++i) a[i] = As[k][ty * 4 + i];
#pragma unroll
            for (int j = 0; j < 4; ++j) bq[j] = Bs[k][tx * 4 + j];
#pragma unroll
            for (int i = 0; i < 4; ++i)
#pragma unroll
                for (int j = 0; j < 4; ++j)
                    acc[i][j] = fmaf(a[i], bq[j], acc[i][j]);
        }
        __syncthreads();
    }

#pragma unroll
    for (int j = 0; j < 4; ++j) {
        const int col = n0 + tx * 4 + j;
        if (col < G_) {
            const float bias = ldw(bih, col, bf) + ldw(bhh, col, bf);
#pragma unroll
            for (int i = 0; i < 4; ++i)
                C[(long)(m0 + ty * 4 + i) * G_ + col] = acc[i][j] + bias;
        }
    }
}

#endif

// ---------------------------------------------------------------------------
// LSTM scan: one WG per (sample, sequence).  grid (128, 2), block 448.
// Weights held PACKED: 50 x u32 (2 bf16 each) per thread -- fits the 64-VGPR
// budget the allocator insists on (rounds 9-11: every residency hint failed;
// 100 fp32 never fit, so it re-loaded 80 KB of uncoalesced rows from L2
// every step).  Unpack is 1 VALU op per weight feeding the FMA directly.
// ---------------------------------------------------------------------------
__global__ __launch_bounds__(448, 2)
void lstm_scan(
    const float* __restrict__ Xg_p, const float* __restrict__ Xg_h,
    const void* __restrict__ whh,
    float* __restrict__ p_h, float* __restrict__ h_h,
    float* __restrict__ px, float* __restrict__ hx, int cat_off,
    const int* __restrict__ flagp)
{
    const int bf = *flagp;
    const int b = blockIdx.x, seq = blockIdx.y;
    const float* Xg = seq ? Xg_h : Xg_p;
    float* hout = seq ? h_h : p_h;
    float* xcat = seq ? hx : px;
    const int g = threadIdx.x;
    const int l = g & 63;

    __shared__ float h_lds[128];             // h (100 used, padded)
    __shared__ float g_lds[400];             // gate pre-activations
    __shared__ float h_hist[S_ * 104];       // h history, flushed at end

    u32 wpk[50];                             // 50 packed bf16 pairs = row g of whh
    float xg = 0.f;
    if (g < G_) {
        if (bf) {
            const u32* w2 = (const u32*)whh;           // bf16 pairs, row-major
#pragma unroll
            for (int j = 0; j < 50; ++j) wpk[j] = w2[g * 50 + j];
        } else {
            const float* wf = (const float*)whh;       // legacy fp32 path
#pragma unroll
            for (int j = 0; j < 50; ++j) {
                u32 lo = f2b(wf[(long)g * 100 + 2 * j]);
                u32 hi = f2b(wf[(long)g * 100 + 2 * j + 1]);
                wpk[j] = lo | (hi << 16);
            }
        }
#pragma unroll
        for (int j = 0; j < 50; ++j) asm volatile("" : "+v"(wpk[j]));  // pin
        xg = Xg[(long)b * G_ + g];
    }
    if (g < 128) h_lds[g] = 0.f;
    float c_reg = 0.f;
    __syncthreads();

    for (int s = 0; s < S_; ++s) {
        // per-wave copy of h (2 LDS reads), broadcast via readlane below
        const float hv0 = h_lds[l];
        const float hv1 = h_lds[l + 64];
        if (g < G_) {
            float a0 = xg, a1 = 0.f, a2 = 0.f, a3 = 0.f;
#pragma unroll
            for (int u = 0; u < 100; u += 4) {
                const u32 p0 = wpk[u >> 1], p1 = wpk[(u >> 1) + 1];
                const float w0 = __int_as_float(p0 << 16);
                const float w1 = __int_as_float(p0 & 0xFFFF0000u);
                const float w2 = __int_as_float(p1 << 16);
                const float w3 = __int_as_float(p1 & 0xFFFF0000u);
                a0 = fmaf(rl(hv0, hv1, u),     w0, a0);
                a1 = fmaf(rl(hv0, hv1, u + 1), w1, a1);
                a2 = fmaf(rl(hv0, hv1, u + 2), w2, a2);
                a3 = fmaf(rl(hv0, hv1, u + 3), w3, a3);
            }
            g_lds[g] = (a0 + a1) + (a2 + a3);
            if (s + 1 < S_) xg = Xg[(long)((s + 1) * B_ + b) * G_ + g];  // prefetch
        }
        __syncthreads();
        if (g < H_) {
            const float iv = fsig(g_lds[g]);
            const float fv = fsig(g_lds[100 + g]);
            const float gv = ftanh(g_lds[200 + g]);
            const float ov = fsig(g_lds[300 + g]);
            c_reg = fv * c_reg + iv * gv;
            const float hv = ov * ftanh(c_reg);
            h_lds[g] = hv;
            h_hist[s * 104 + g] = hv;
        }
        __syncthreads();
    }

    // coalesced flush of the whole h history
    for (int i = g; i < S_ * H_; i += 448) {
        const int s = i / H_, d = i - s * H_;
        const float hv = h_hist[s * 104 + d];
        hout[(long)(s * B_ + b) * H_ + d] = hv;
        if (cat_off >= 0) xcat[(long)(s * B_ + b) * PXP + cat_off + d] = hv;
    }
}

// ---------------------------------------------------------------------------
// Cross attention for one batch sample.  grid (128), block 256.
// ---------------------------------------------------------------------------
__global__ __launch_bounds__(256) void attn_kernel(
    const float* __restrict__ p_h, const float* __restrict__ h_h,
    float* __restrict__ px, float* __restrict__ hx, int off)
{
    const int b = blockIdx.x, t = threadIdx.x;
    __shared__ float P[4800], Q[4800], A[2304], Sx[2304];

    for (int i = t; i < 4800; i += 256) {
        const int s = i / 100, d = i % 100;
        P[i] = p_h[(long)(s * B_ + b) * H_ + d];
        Q[i] = h_h[(long)(s * B_ + b) * H_ + d];
    }
    __syncthreads();

    for (int e = t; e < 2304; e += 256) {
        const int p = e / 48, q = e % 48;
        float acc = 0.f;
        for (int j = 0; j < 100; ++j) acc = fmaf(P[p * 100 + j], Q[q * 100 + j], acc);
        A[e] = acc;
    }
    __syncthreads();

    if (t < 48) {  // row softmax
        float m = -1e30f;
        for (int q = 0; q < 48; ++q) m = fmaxf(m, A[t * 48 + q]);
        float sum = 0.f;
        for (int q = 0; q < 48; ++q) sum += expf(A[t * 48 + q] - m);
        const float inv = 1.f / sum;
        for (int q = 0; q < 48; ++q) Sx[t * 48 + q] = expf(A[t * 48 + q] - m) * inv;
    }
    __syncthreads();

    for (int e = t; e < 4800; e += 256) {  // a_p = S @ Q
        const int p = e / 100, d = e % 100;
        float acc = 0.f;
        for (int q = 0; q < 48; ++q) acc = fmaf(Sx[p * 48 + q], Q[q * 100 + d], acc);
        px[(long)(p * B_ + b) * PXP + off + d] = acc;
    }
    __syncthreads();

    if (t < 48) {  // col softmax
        float m = -1e30f;
        for (int p = 0; p < 48; ++p) m = fmaxf(m, A[p * 48 + t]);
        float sum = 0.f;
        for (int p = 0; p < 48; ++p) sum += expf(A[p * 48 + t] - m);
        const float inv = 1.f / sum;
        for (int p = 0; p < 48; ++p) Sx[p * 48 + t] = expf(A[p * 48 + t] - m) * inv;
    }
    __syncthreads();

    for (int e = t; e < 4800; e += 256) {  // a_h[q] = sum_p S2[p][q] * P[p]
        const int q = e / 100, d = e % 100;
        float acc = 0.f;
        for (int p = 0; p < 48; ++p) acc = fmaf(Sx[p * 48 + q], P[p * 100 + d], acc);
        hx[(long)(q * B_ + b) * PXP + off + d] = acc;
    }
}

// ---------------------------------------------------------------------------
// Pool + feature build.
// ---------------------------------------------------------------------------
__global__ __launch_bounds__(256) void pool_feats(
    const float* __restrict__ p_h, const float* __restrict__ h_h,
    float* __restrict__ feats)
{
    const int t = blockIdx.x * 256 + threadIdx.x;
    if (t >= B_ * H_) return;
    const int b = t / H_, u = t % H_;
    float hq = -1e30f, hs = -1e30f;
    for (int s = 0; s < S_; ++s) {
        hq = fmaxf(hq, p_h[(long)(s * B_ + b) * H_ + u]);
        hs = fmaxf(hs, h_h[(long)(s * B_ + b) * H_ + u]);
    }
    float* f = feats + b * 500;
    f[u]       = hq;
    f[100 + u] = hs;
    f[200 + u] = hs - hq;
    f[300 + u] = hq * hs;
    f[400 + u] = fabsf(hq - hs);
}

// ---------------------------------------------------------------------------
// z = relu(feats @ fcl_w^T + fcl_b).
// ---------------------------------------------------------------------------
__global__ __launch_bounds__(256) void fcl_kernel(
    const float* __restrict__ feats, const void* __restrict__ fw,
    const void* __restrict__ fb, float* __restrict__ z, const int* __restrict__ flagp)
{
    const int bf = *flagp;
    const int t = blockIdx.x * 256 + threadIdx.x;
    const int o = t >> 7, b = t & 127;
    float acc = ldw(fb, o, bf);
    const float* f = feats + b * 500;
    for (int d = 0; d < 500; ++d) acc = fmaf(f[d], ldw(fw, (long)o * 500 + d, bf), acc);
    z[b * 800 + o] = fmaxf(acc, 0.f);
}

// ---------------------------------------------------------------------------
// out = sigmoid(z @ last_w^T + last_b).  Output dtype follows flag.
// ---------------------------------------------------------------------------
__global__ __launch_bounds__(256) void last_kernel(
    const float* __restrict__ z, const void* __restrict__ lw,
    const void* __restrict__ lb, void* __restrict__ out, const int* __restrict__ flagp)
{
    const int bf = *flagp;
    const int t = threadIdx.x;
    const int b = t >> 1, c = t & 1;
    float acc = ldw(lb, c, bf);
    const float* zr = z + b * 800;
    for (int o = 0; o < 800; ++o) acc = fmaf(zr[o], ldw(lw, (long)c * 800 + o, bf), acc);
    const float v = 1.f / (1.f + expf(-acc));
    if (bf) ((u16*)out)[t] = f2b(v);
    else    ((float*)out)[t] = v;
}

// ---------------------------------------------------------------------------
extern "C" void kernel_launch(void* const* d_in, const int* in_sizes, int n_in,
                              void* d_out, int out_size, void* d_ws, size_t ws_size,
                              hipStream_t stream)
{
    (void)in_sizes; (void)n_in; (void)out_size; (void)ws_size;

    const int* qw = (const int*)d_in[0];
    const int* qc = (const int*)d_in[1];
    const int* sw = (const int*)d_in[2];
    const int* sc = (const int*)d_in[3];
    const void* wemb = d_in[4];
    const void* cemb = d_in[5];
    const void* cw   = d_in[6];
    const void* cb   = d_in[7];
    const void* fclw = d_in[28];
    const void* fclb = d_in[29];
    const void* lw   = d_in[30];
    const void* lb   = d_in[31];

    float* ws = (float*)d_ws;
    int*  flag = (int*)ws;                               // [16] floats reserved
    float* px   = ws + 16;
    float* hx   = px + (long)S_ * B_ * PXP;
    float* Xg_p = hx + (long)S_ * B_ * PXP;
    float* Xg_h = Xg_p + (long)S_ * B_ * G_;
    float* p_h  = Xg_h + (long)S_ * B_ * G_;
    float* h_h  = p_h + (long)S_ * B_ * H_;
    float* feats = h_h + (long)S_ * B_ * H_;
    float* z    = feats + B_ * 500;

    detect_kernel<<<dim3(1), 256, 0, stream>>>(wemb, flag);

    embed_kernel<<<dim3(B_, S_, 2), 64, 0, stream>>>(qw, qc, sw, sc, wemb, cemb, cw, cb, px, hx, flag);

    for (int k = 0; k < 5; ++k) {
        const void* wih = d_in[8 + 4 * k];
        const void* whh = d_in[9 + 4 * k];
        const void* bih = d_in[10 + 4 * k];
        const void* bhh = d_in[11 + 4 * k];
        const int K = 316 + 200 * k;

        gemm_wih<<<dim3(96, 7, 2), 256, 0, stream>>>(px, hx, Xg_p, Xg_h, wih, bih, bhh, K, flag);

        const int cat = (k < 4) ? (K + 100) : -1;
        lstm_scan<<<dim3(B_, 2), 448, 0, stream>>>(Xg_p, Xg_h, whh, p_h, h_h, px, hx, cat, flag);

        if (k < 4)
            attn_kernel<<<dim3(B_), 256, 0, stream>>>(p_h, h_h, px, hx, K);
    }

    pool_feats<<<dim3(50), 256, 0, stream>>>(p_h, h_h, feats);
    fcl_kernel<<<dim3(400), 256, 0, stream>>>(feats, fclw, fclb, z, flag);
    last_kernel<<<dim3(1), 256, 0, stream>>>(z, lw, lb, d_out, flag);
}